// Round 5
// baseline (553.228 us; speedup 1.0000x reference)
//
#include <hip/hip_runtime.h>
#include <math.h>

// Problem constants (fixed by setup_inputs):
// B=2, W=12, N=10000, F=16, HID=32, H=2, M=B*N=20000
// E0 total = 320000 edges; +M self loops => E_TOT = 340000
// Only t=10 and t=11 feed the final output (conv tail, last position).
#define M_NODES 20000
#define N_PER_B 10000
#define E0T     320000
#define E_TOT   340000

// ---------------- CSR build ----------------

__global__ void hist_kernel(const int* __restrict__ eidx, int* __restrict__ cnt) {
    int e = blockIdx.x * blockDim.x + threadIdx.x;
    if (e >= E_TOT) return;
    int d = (e < E0T) ? eidx[E0T + e] : (e - E0T);
    atomicAdd(&cnt[d], 1);
}

__global__ void scan_kernel(const int* __restrict__ cnt, int* __restrict__ offsets,
                            int* __restrict__ cursor) {
    __shared__ int sdata[1024];
    const int CHUNK = 20; // 1024*20 = 20480 >= 20000
    int tid = threadIdx.x;
    int begin = tid * CHUNK;
    int end = begin + CHUNK; if (end > M_NODES) end = M_NODES;
    if (begin > M_NODES) begin = M_NODES;
    int s = 0;
    for (int i = begin; i < end; ++i) s += cnt[i];
    sdata[tid] = s;
    __syncthreads();
    for (int off = 1; off < 1024; off <<= 1) {
        int v = (tid >= off) ? sdata[tid - off] : 0;
        __syncthreads();
        sdata[tid] += v;
        __syncthreads();
    }
    int run = (tid == 0) ? 0 : sdata[tid - 1];
    for (int i = begin; i < end; ++i) {
        offsets[i] = run; cursor[i] = run; run += cnt[i];
    }
    if (tid == 1023) offsets[M_NODES] = sdata[1023];
}

__global__ void scatter_kernel(const int* __restrict__ eidx, int* __restrict__ cursor,
                               int* __restrict__ ssrc) {
    int e = blockIdx.x * blockDim.x + threadIdx.x;
    if (e >= E_TOT) return;
    int s, d;
    if (e < E0T) { s = eidx[e]; d = eidx[E0T + e]; }
    else         { s = e - E0T; d = s; }
    int pos = atomicAdd(&cursor[d], 1);
    ssrc[pos] = s;
}

// Deterministic CSR: sort each dst bucket by src (duplicates equal -> fp-stable).
__global__ void sort_kernel(const int* __restrict__ offsets, int* __restrict__ ssrc) {
    int m = blockIdx.x * blockDim.x + threadIdx.x;
    if (m >= M_NODES) return;
    int s = offsets[m], e = offsets[m + 1];
    for (int i = s + 1; i < e; ++i) {
        int v = ssrc[i]; int j = i - 1;
        while (j >= s && ssrc[j] > v) { ssrc[j + 1] = ssrc[j]; --j; }
        ssrc[j + 1] = v;
    }
}

// ---------------- fold W1 @ as1 / ad1 -> wfold[16][2][2] ----------------
__global__ void fold1_kernel(const float* __restrict__ W1, const float* __restrict__ as1,
                             const float* __restrict__ ad1, float* __restrict__ wfold) {
    int t = threadIdx.x;
    if (t >= 32) return;
    int f = t >> 1, h = t & 1;
    float ss = 0.f, dd = 0.f;
    for (int c = 0; c < 32; ++c) {
        float w = W1[f * 64 + h * 32 + c];
        ss += w * as1[h * 32 + c];
        dd += w * ad1[h * 32 + c];
    }
    wfold[(f * 2 + h) * 2 + 0] = ss;
    wfold[(f * 2 + h) * 2 + 1] = dd;
}

// ---------------- layer-1 attention logits directly from x ----------------
__global__ void logits1_kernel(const float* __restrict__ x, const float* __restrict__ wfold,
                               float* __restrict__ asv, float* __restrict__ adv, int tt) {
    int idx = blockIdx.x * blockDim.x + threadIdx.x; // m*2+h
    if (idx >= M_NODES * 2) return;
    int m = idx >> 1, h = idx & 1;
    int b = m / N_PER_B, n = m - b * N_PER_B;
    const float* xr = x + ((size_t)((b * 12 + 10 + tt) * N_PER_B + n)) * 16;
    float ss = 0.f, dd = 0.f;
    #pragma unroll
    for (int f = 0; f < 16; ++f) {
        ss += xr[f] * wfold[(f * 2 + h) * 2 + 0];
        dd += xr[f] * wfold[(f * 2 + h) * 2 + 1];
    }
    asv[idx] = ss; adv[idx] = dd;
}

// ---------------- layer-1 softmax-aggregate, h1 recomputed on the fly ----------------
__global__ void agg1_kernel(const int* __restrict__ offsets, const int* __restrict__ ssrc,
                            const float* __restrict__ x, const float* __restrict__ W1,
                            const float* __restrict__ asv, const float* __restrict__ adv,
                            const float* __restrict__ b1, float* __restrict__ out1, int tt) {
    int w = (blockIdx.x * blockDim.x + threadIdx.x) >> 6;
    int lane = threadIdx.x & 63;
    if (w >= M_NODES) return;
    int m = w;
    int head = lane >> 5, k = lane & 31;
    float w1c[16];
    #pragma unroll
    for (int f = 0; f < 16; ++f) w1c[f] = W1[f * 64 + lane];
    int start = offsets[m], end = offsets[m + 1];
    float ad = adv[m * 2 + head];
    float mx = -1e30f;
    for (int e = start + k; e < end; e += 32) {
        float v = asv[ssrc[e] * 2 + head] + ad;
        v = v > 0.f ? v : 0.2f * v;
        mx = fmaxf(mx, v);
    }
    #pragma unroll
    for (int off = 16; off >= 1; off >>= 1) mx = fmaxf(mx, __shfl_xor(mx, off, 64));
    float sm = 0.f;
    for (int e = start + k; e < end; e += 32) {
        float v = asv[ssrc[e] * 2 + head] + ad;
        v = v > 0.f ? v : 0.2f * v;
        sm += expf(v - mx);
    }
    #pragma unroll
    for (int off = 16; off >= 1; off >>= 1) sm += __shfl_xor(sm, off, 64);
    float inv = 1.f / sm;
    float acc = 0.f;
    for (int e = start; e < end; ++e) {
        int s = ssrc[e];
        float v = asv[s * 2 + head] + ad;
        v = v > 0.f ? v : 0.2f * v;
        float wgt = expf(v - mx) * inv;
        int b = s / N_PER_B, n = s - b * N_PER_B;
        const float* xr = x + ((size_t)((b * 12 + 10 + tt) * N_PER_B + n)) * 16;
        float xv = (lane < 16) ? xr[lane] : 0.f;
        float h = 0.f;
        #pragma unroll
        for (int f = 0; f < 16; ++f) h += __shfl(xv, f, 64) * w1c[f];
        acc += wgt * h;
    }
    float r = acc + b1[lane];
    out1[(size_t)m * 64 + lane] = r > 0.f ? r : 0.f;
}

// ---------------- layer-2 projection + logits ----------------
__global__ void proj2_kernel(const float* __restrict__ out1, const float* __restrict__ W2,
                             const float* __restrict__ as2, const float* __restrict__ ad2,
                             float* __restrict__ h2p, float* __restrict__ asv, float* __restrict__ adv) {
    int w = (blockIdx.x * blockDim.x + threadIdx.x) >> 6;
    int lane = threadIdx.x & 63;
    if (w >= M_NODES) return;
    float xv = out1[(size_t)w * 64 + lane];
    float acc = 0.f;
    #pragma unroll
    for (int f = 0; f < 64; ++f) acc += __shfl(xv, f, 64) * W2[f * 64 + lane];
    h2p[(size_t)w * 64 + lane] = acc;
    float sv = acc * as2[lane];
    float dv = acc * ad2[lane];
    #pragma unroll
    for (int off = 16; off >= 1; off >>= 1) {
        sv += __shfl_xor(sv, off, 64);
        dv += __shfl_xor(dv, off, 64);
    }
    if ((lane & 31) == 0) {
        asv[w * 2 + (lane >> 5)] = sv;
        adv[w * 2 + (lane >> 5)] = dv;
    }
}

// ---------------- layer-2 softmax-aggregate (mean heads) ----------------
__global__ void agg2_kernel(const int* __restrict__ offsets, const int* __restrict__ ssrc,
                            const float* __restrict__ h2p, const float* __restrict__ asv,
                            const float* __restrict__ adv, const float* __restrict__ b2,
                            float* __restrict__ h2, int tt) {
    int w = (blockIdx.x * blockDim.x + threadIdx.x) >> 6;
    int lane = threadIdx.x & 63;
    if (w >= M_NODES) return;
    int m = w;
    int head = lane >> 5, k = lane & 31;
    int start = offsets[m], end = offsets[m + 1];
    float ad = adv[m * 2 + head];
    float mx = -1e30f;
    for (int e = start + k; e < end; e += 32) {
        float v = asv[ssrc[e] * 2 + head] + ad;
        v = v > 0.f ? v : 0.2f * v;
        mx = fmaxf(mx, v);
    }
    #pragma unroll
    for (int off = 16; off >= 1; off >>= 1) mx = fmaxf(mx, __shfl_xor(mx, off, 64));
    float sm = 0.f;
    for (int e = start + k; e < end; e += 32) {
        float v = asv[ssrc[e] * 2 + head] + ad;
        v = v > 0.f ? v : 0.2f * v;
        sm += expf(v - mx);
    }
    #pragma unroll
    for (int off = 16; off >= 1; off >>= 1) sm += __shfl_xor(sm, off, 64);
    float inv = 1.f / sm;
    float acc = 0.f;
    for (int e = start; e < end; ++e) {
        int s = ssrc[e];
        float v = asv[s * 2 + head] + ad;
        v = v > 0.f ? v : 0.2f * v;
        acc += expf(v - mx) * inv * h2p[(size_t)s * 64 + lane];
    }
    float other = __shfl_xor(acc, 32, 64);
    if (lane < 32) {
        float r = 0.5f * (acc + other) + b2[lane];
        h2[((size_t)tt * M_NODES + m) * 32 + lane] = r > 0.f ? r : 0.f;
    }
}

// ---------------- fused conv tail (last position) + FC ----------------
__global__ void final_kernel(const float* __restrict__ h2, const float* __restrict__ wconv,
                             const float* __restrict__ bconv, const float* __restrict__ wfc,
                             const float* __restrict__ bfc, float* __restrict__ out) {
    int w = (blockIdx.x * blockDim.x + threadIdx.x) >> 6;
    int lane = threadIdx.x & 63;
    if (w >= M_NODES) return;
    int m = w;
    int i = lane & 31, half = lane >> 5;  // half 0 -> t=10 (k=0), half 1 -> t=11 (k=1)
    float hv = h2[((size_t)half * M_NODES + m) * 32 + i];
    float acc = 0.f;
    for (int co = 0; co < 32; ++co) {
        float p = hv * wconv[(co * 32 + i) * 3 + half];
        #pragma unroll
        for (int off = 32; off >= 1; off >>= 1) p += __shfl_xor(p, off, 64);
        float t = p + bconv[co];
        t = t > 0.f ? t : 0.f;
        acc += t * wfc[co];
    }
    if (lane == 0) out[m] = acc + bfc[0];
}

extern "C" void kernel_launch(void* const* d_in, const int* in_sizes, int n_in,
                              void* d_out, int out_size, void* d_ws, size_t ws_size,
                              hipStream_t stream) {
    const float* x     = (const float*)d_in[0];
    const int*   eidx  = (const int*)d_in[1];
    const float* W1    = (const float*)d_in[2];
    const float* as1   = (const float*)d_in[3];
    const float* ad1   = (const float*)d_in[4];
    const float* b1    = (const float*)d_in[5];
    const float* W2    = (const float*)d_in[6];
    const float* as2   = (const float*)d_in[7];
    const float* ad2   = (const float*)d_in[8];
    const float* b2    = (const float*)d_in[9];
    const float* wconv = (const float*)d_in[10];
    const float* bconv = (const float*)d_in[11];
    const float* wfc   = (const float*)d_in[12];
    const float* bfc   = (const float*)d_in[13];
    float* out = (float*)d_out;

    // Workspace layout — total ~17.3 MB (kept well under ws_size).
    char* ws = (char*)d_ws;
    auto alloc = [&](size_t bytes) -> char* {
        char* p = ws;
        ws += (bytes + 255) & ~(size_t)255;
        return p;
    };
    int*   cnt     = (int*)alloc((M_NODES + 1) * sizeof(int));     // 80 KB
    int*   offsets = (int*)alloc((M_NODES + 1) * sizeof(int));     // 80 KB
    int*   cursor  = (int*)alloc((M_NODES + 1) * sizeof(int));     // 80 KB
    int*   ssrc    = (int*)alloc((size_t)E_TOT * sizeof(int));     // 1.36 MB
    float* wfold   = (float*)alloc(16 * 2 * 2 * sizeof(float));    // 256 B
    float* asv     = (float*)alloc((size_t)M_NODES * 2 * sizeof(float)); // 160 KB (reused L1/L2)
    float* adv     = (float*)alloc((size_t)M_NODES * 2 * sizeof(float)); // 160 KB
    float* out1    = (float*)alloc((size_t)M_NODES * 64 * sizeof(float)); // 5.12 MB (per-t)
    float* h2p     = (float*)alloc((size_t)M_NODES * 64 * sizeof(float)); // 5.12 MB (per-t)
    float* h2      = (float*)alloc((size_t)2 * M_NODES * 32 * sizeof(float)); // 5.12 MB (both t)

    hipMemsetAsync(cnt, 0, (M_NODES + 1) * sizeof(int), stream);

    int ethreads = 256, eblocks = (E_TOT + ethreads - 1) / ethreads;
    hist_kernel<<<eblocks, ethreads, 0, stream>>>(eidx, cnt);
    scan_kernel<<<1, 1024, 0, stream>>>(cnt, offsets, cursor);
    scatter_kernel<<<eblocks, ethreads, 0, stream>>>(eidx, cursor, ssrc);
    sort_kernel<<<(M_NODES + 255) / 256, 256, 0, stream>>>(offsets, ssrc);
    fold1_kernel<<<1, 64, 0, stream>>>(W1, as1, ad1, wfold);

    int blocks_m = (M_NODES * 64) / 256;      // 5000 blocks, 1 wave per node
    int lblocks  = (M_NODES * 2 + 255) / 256; // logits threads

    for (int tt = 0; tt < 2; ++tt) {
        logits1_kernel<<<lblocks, 256, 0, stream>>>(x, wfold, asv, adv, tt);
        agg1_kernel<<<blocks_m, 256, 0, stream>>>(offsets, ssrc, x, W1, asv, adv, b1, out1, tt);
        proj2_kernel<<<blocks_m, 256, 0, stream>>>(out1, W2, as2, ad2, h2p, asv, adv);
        agg2_kernel<<<blocks_m, 256, 0, stream>>>(offsets, ssrc, h2p, asv, adv, b2, h2, tt);
    }

    final_kernel<<<blocks_m, 256, 0, stream>>>(h2, wconv, bconv, wfc, bfc, out);
}

// Round 8
// 478.936 us; speedup vs baseline: 1.1551x; 1.1551x over previous
//
#include <hip/hip_runtime.h>
#include <math.h>

// Problem constants (fixed by setup_inputs):
// B=2, W=12, N=10000, F=16, HID=32, H=2, M=B*N=20000
// E0 total = 320000 edges; +M self loops => E_TOT = 340000
// Only t=10 and t=11 feed the final output (conv tail, last position).
#define M_NODES 20000
#define N_PER_B 10000
#define E0T     320000
#define E_TOT   340000

// ---------------- CSR build ----------------

__global__ void hist_kernel(const int* __restrict__ eidx, int* __restrict__ cnt) {
    int e = blockIdx.x * blockDim.x + threadIdx.x;
    if (e >= E_TOT) return;
    int d = (e < E0T) ? eidx[E0T + e] : (e - E0T);
    atomicAdd(&cnt[d], 1);
}

__global__ void scan_kernel(const int* __restrict__ cnt, int* __restrict__ offsets,
                            int* __restrict__ cursor) {
    __shared__ int sdata[1024];
    const int CHUNK = 20; // 1024*20 = 20480 >= 20000
    int tid = threadIdx.x;
    int begin = tid * CHUNK;
    int end = begin + CHUNK; if (end > M_NODES) end = M_NODES;
    if (begin > M_NODES) begin = M_NODES;
    int s = 0;
    for (int i = begin; i < end; ++i) s += cnt[i];
    sdata[tid] = s;
    __syncthreads();
    for (int off = 1; off < 1024; off <<= 1) {
        int v = (tid >= off) ? sdata[tid - off] : 0;
        __syncthreads();
        sdata[tid] += v;
        __syncthreads();
    }
    int run = (tid == 0) ? 0 : sdata[tid - 1];
    for (int i = begin; i < end; ++i) {
        offsets[i] = run; cursor[i] = run; run += cnt[i];
    }
    if (tid == 1023) offsets[M_NODES] = sdata[1023];
}

__global__ void scatter_kernel(const int* __restrict__ eidx, int* __restrict__ cursor,
                               int* __restrict__ ssrc) {
    int e = blockIdx.x * blockDim.x + threadIdx.x;
    if (e >= E_TOT) return;
    int s, d;
    if (e < E0T) { s = eidx[e]; d = eidx[E0T + e]; }
    else         { s = e - E0T; d = s; }
    int pos = atomicAdd(&cursor[d], 1);
    ssrc[pos] = s;
}

// Deterministic CSR: sort each dst bucket by src.
// One WAVE per bucket, bitonic sort across 64 lanes (avg deg 17, max ~40).
// Serial fallback on lane 0 if a bucket somehow exceeds 64.
__global__ void sort_kernel(const int* __restrict__ offsets, int* __restrict__ ssrc) {
    int w = (blockIdx.x * blockDim.x + threadIdx.x) >> 6;
    int lane = threadIdx.x & 63;
    if (w >= M_NODES) return;
    int s = offsets[w], e = offsets[w + 1];
    int len = e - s;
    if (len <= 1) return;
    if (len <= 64) {
        int v = (lane < len) ? ssrc[s + lane] : 0x7fffffff;
        #pragma unroll
        for (int k = 2; k <= 64; k <<= 1) {
            #pragma unroll
            for (int j = k >> 1; j > 0; j >>= 1) {
                int partner = __shfl_xor(v, j, 64);
                bool ascending = ((lane & k) == 0);
                bool lower = ((lane & j) == 0);
                bool keepMin = (lower == ascending);
                v = keepMin ? min(v, partner) : max(v, partner);
            }
        }
        if (lane < len) ssrc[s + lane] = v;
    } else if (lane == 0) {
        for (int i = s + 1; i < e; ++i) {
            int v = ssrc[i]; int j = i - 1;
            while (j >= s && ssrc[j] > v) { ssrc[j + 1] = ssrc[j]; --j; }
            ssrc[j + 1] = v;
        }
    }
}

// ---------------- fold W1 @ as1 / ad1 -> wfold[16][2][2] ----------------
__global__ void fold1_kernel(const float* __restrict__ W1, const float* __restrict__ as1,
                             const float* __restrict__ ad1, float* __restrict__ wfold) {
    int t = threadIdx.x;
    if (t >= 32) return;
    int f = t >> 1, h = t & 1;
    float ss = 0.f, dd = 0.f;
    for (int c = 0; c < 32; ++c) {
        float w = W1[f * 64 + h * 32 + c];
        ss += w * as1[h * 32 + c];
        dd += w * ad1[h * 32 + c];
    }
    wfold[(f * 2 + h) * 2 + 0] = ss;
    wfold[(f * 2 + h) * 2 + 1] = dd;
}

// ---------------- layer-1 attention logits directly from x ----------------
__global__ void logits1_kernel(const float* __restrict__ x, const float* __restrict__ wfold,
                               float* __restrict__ asv, float* __restrict__ adv, int tt) {
    int idx = blockIdx.x * blockDim.x + threadIdx.x; // m*2+h
    if (idx >= M_NODES * 2) return;
    int m = idx >> 1, h = idx & 1;
    int b = m / N_PER_B, n = m - b * N_PER_B;
    const float* xr = x + ((size_t)((b * 12 + 10 + tt) * N_PER_B + n)) * 16;
    float ss = 0.f, dd = 0.f;
    #pragma unroll
    for (int f = 0; f < 16; ++f) {
        ss += xr[f] * wfold[(f * 2 + h) * 2 + 0];
        dd += xr[f] * wfold[(f * 2 + h) * 2 + 1];
    }
    asv[idx] = ss; adv[idx] = dd;
}

// ---------------- layer-1 softmax-aggregate, h1 recomputed on the fly ----------------
__global__ void agg1_kernel(const int* __restrict__ offsets, const int* __restrict__ ssrc,
                            const float* __restrict__ x, const float* __restrict__ W1,
                            const float* __restrict__ asv, const float* __restrict__ adv,
                            const float* __restrict__ b1, float* __restrict__ out1, int tt) {
    int w = (blockIdx.x * blockDim.x + threadIdx.x) >> 6;
    int lane = threadIdx.x & 63;
    if (w >= M_NODES) return;
    int m = w;
    int head = lane >> 5, k = lane & 31;
    float w1c[16];
    #pragma unroll
    for (int f = 0; f < 16; ++f) w1c[f] = W1[f * 64 + lane];
    int start = offsets[m], end = offsets[m + 1];
    float ad = adv[m * 2 + head];
    float mx = -1e30f;
    for (int e = start + k; e < end; e += 32) {
        float v = asv[ssrc[e] * 2 + head] + ad;
        v = v > 0.f ? v : 0.2f * v;
        mx = fmaxf(mx, v);
    }
    #pragma unroll
    for (int off = 16; off >= 1; off >>= 1) mx = fmaxf(mx, __shfl_xor(mx, off, 64));
    float sm = 0.f;
    for (int e = start + k; e < end; e += 32) {
        float v = asv[ssrc[e] * 2 + head] + ad;
        v = v > 0.f ? v : 0.2f * v;
        sm += expf(v - mx);
    }
    #pragma unroll
    for (int off = 16; off >= 1; off >>= 1) sm += __shfl_xor(sm, off, 64);
    float inv = 1.f / sm;
    float acc = 0.f;
    for (int e = start; e < end; ++e) {
        int s = ssrc[e];
        float v = asv[s * 2 + head] + ad;
        v = v > 0.f ? v : 0.2f * v;
        float wgt = expf(v - mx) * inv;
        int b = s / N_PER_B, n = s - b * N_PER_B;
        const float* xr = x + ((size_t)((b * 12 + 10 + tt) * N_PER_B + n)) * 16;
        float xv = (lane < 16) ? xr[lane] : 0.f;
        float h = 0.f;
        #pragma unroll
        for (int f = 0; f < 16; ++f) h += __shfl(xv, f, 64) * w1c[f];
        acc += wgt * h;
    }
    float r = acc + b1[lane];
    out1[(size_t)m * 64 + lane] = r > 0.f ? r : 0.f;
}

// ---------------- layer-2 projection + logits ----------------
__global__ void proj2_kernel(const float* __restrict__ out1, const float* __restrict__ W2,
                             const float* __restrict__ as2, const float* __restrict__ ad2,
                             float* __restrict__ h2p, float* __restrict__ asv, float* __restrict__ adv) {
    int w = (blockIdx.x * blockDim.x + threadIdx.x) >> 6;
    int lane = threadIdx.x & 63;
    if (w >= M_NODES) return;
    float xv = out1[(size_t)w * 64 + lane];
    float acc = 0.f;
    #pragma unroll
    for (int f = 0; f < 64; ++f) acc += __shfl(xv, f, 64) * W2[f * 64 + lane];
    h2p[(size_t)w * 64 + lane] = acc;
    float sv = acc * as2[lane];
    float dv = acc * ad2[lane];
    #pragma unroll
    for (int off = 16; off >= 1; off >>= 1) {
        sv += __shfl_xor(sv, off, 64);
        dv += __shfl_xor(dv, off, 64);
    }
    if ((lane & 31) == 0) {
        asv[w * 2 + (lane >> 5)] = sv;
        adv[w * 2 + (lane >> 5)] = dv;
    }
}

// ---------------- layer-2 softmax-aggregate (mean heads) ----------------
__global__ void agg2_kernel(const int* __restrict__ offsets, const int* __restrict__ ssrc,
                            const float* __restrict__ h2p, const float* __restrict__ asv,
                            const float* __restrict__ adv, const float* __restrict__ b2,
                            float* __restrict__ h2, int tt) {
    int w = (blockIdx.x * blockDim.x + threadIdx.x) >> 6;
    int lane = threadIdx.x & 63;
    if (w >= M_NODES) return;
    int m = w;
    int head = lane >> 5, k = lane & 31;
    int start = offsets[m], end = offsets[m + 1];
    float ad = adv[m * 2 + head];
    float mx = -1e30f;
    for (int e = start + k; e < end; e += 32) {
        float v = asv[ssrc[e] * 2 + head] + ad;
        v = v > 0.f ? v : 0.2f * v;
        mx = fmaxf(mx, v);
    }
    #pragma unroll
    for (int off = 16; off >= 1; off >>= 1) mx = fmaxf(mx, __shfl_xor(mx, off, 64));
    float sm = 0.f;
    for (int e = start + k; e < end; e += 32) {
        float v = asv[ssrc[e] * 2 + head] + ad;
        v = v > 0.f ? v : 0.2f * v;
        sm += expf(v - mx);
    }
    #pragma unroll
    for (int off = 16; off >= 1; off >>= 1) sm += __shfl_xor(sm, off, 64);
    float inv = 1.f / sm;
    float acc = 0.f;
    for (int e = start; e < end; ++e) {
        int s = ssrc[e];
        float v = asv[s * 2 + head] + ad;
        v = v > 0.f ? v : 0.2f * v;
        acc += expf(v - mx) * inv * h2p[(size_t)s * 64 + lane];
    }
    float other = __shfl_xor(acc, 32, 64);
    if (lane < 32) {
        float r = 0.5f * (acc + other) + b2[lane];
        h2[((size_t)tt * M_NODES + m) * 32 + lane] = r > 0.f ? r : 0.f;
    }
}

// ---------------- fused conv tail (last position) + FC ----------------
__global__ void final_kernel(const float* __restrict__ h2, const float* __restrict__ wconv,
                             const float* __restrict__ bconv, const float* __restrict__ wfc,
                             const float* __restrict__ bfc, float* __restrict__ out) {
    int w = (blockIdx.x * blockDim.x + threadIdx.x) >> 6;
    int lane = threadIdx.x & 63;
    if (w >= M_NODES) return;
    int m = w;
    int i = lane & 31, half = lane >> 5;  // half 0 -> t=10 (k=0), half 1 -> t=11 (k=1)
    float hv = h2[((size_t)half * M_NODES + m) * 32 + i];
    float acc = 0.f;
    for (int co = 0; co < 32; ++co) {
        float p = hv * wconv[(co * 32 + i) * 3 + half];
        #pragma unroll
        for (int off = 32; off >= 1; off >>= 1) p += __shfl_xor(p, off, 64);
        float t = p + bconv[co];
        t = t > 0.f ? t : 0.f;
        acc += t * wfc[co];
    }
    if (lane == 0) out[m] = acc + bfc[0];
}

extern "C" void kernel_launch(void* const* d_in, const int* in_sizes, int n_in,
                              void* d_out, int out_size, void* d_ws, size_t ws_size,
                              hipStream_t stream) {
    const float* x     = (const float*)d_in[0];
    const int*   eidx  = (const int*)d_in[1];
    const float* W1    = (const float*)d_in[2];
    const float* as1   = (const float*)d_in[3];
    const float* ad1   = (const float*)d_in[4];
    const float* b1    = (const float*)d_in[5];
    const float* W2    = (const float*)d_in[6];
    const float* as2   = (const float*)d_in[7];
    const float* ad2   = (const float*)d_in[8];
    const float* b2    = (const float*)d_in[9];
    const float* wconv = (const float*)d_in[10];
    const float* bconv = (const float*)d_in[11];
    const float* wfc   = (const float*)d_in[12];
    const float* bfc   = (const float*)d_in[13];
    float* out = (float*)d_out;

    // Workspace layout — total ~17.3 MB (kept well under ws_size).
    char* ws = (char*)d_ws;
    auto alloc = [&](size_t bytes) -> char* {
        char* p = ws;
        ws += (bytes + 255) & ~(size_t)255;
        return p;
    };
    int*   cnt     = (int*)alloc((M_NODES + 1) * sizeof(int));     // 80 KB
    int*   offsets = (int*)alloc((M_NODES + 1) * sizeof(int));     // 80 KB
    int*   cursor  = (int*)alloc((M_NODES + 1) * sizeof(int));     // 80 KB
    int*   ssrc    = (int*)alloc((size_t)E_TOT * sizeof(int));     // 1.36 MB
    float* wfold   = (float*)alloc(16 * 2 * 2 * sizeof(float));    // 256 B
    float* asv     = (float*)alloc((size_t)M_NODES * 2 * sizeof(float)); // 160 KB
    float* adv     = (float*)alloc((size_t)M_NODES * 2 * sizeof(float)); // 160 KB
    float* out1    = (float*)alloc((size_t)M_NODES * 64 * sizeof(float)); // 5.12 MB (per-t)
    float* h2p     = (float*)alloc((size_t)M_NODES * 64 * sizeof(float)); // 5.12 MB (per-t)
    float* h2      = (float*)alloc((size_t)2 * M_NODES * 32 * sizeof(float)); // 5.12 MB (both t)

    hipMemsetAsync(cnt, 0, (M_NODES + 1) * sizeof(int), stream);

    int ethreads = 256, eblocks = (E_TOT + ethreads - 1) / ethreads;
    hist_kernel<<<eblocks, ethreads, 0, stream>>>(eidx, cnt);
    scan_kernel<<<1, 1024, 0, stream>>>(cnt, offsets, cursor);
    scatter_kernel<<<eblocks, ethreads, 0, stream>>>(eidx, cursor, ssrc);
    // one wave per bucket: 20000 waves -> 5000 blocks of 256
    sort_kernel<<<(M_NODES * 64) / 256, 256, 0, stream>>>(offsets, ssrc);
    fold1_kernel<<<1, 64, 0, stream>>>(W1, as1, ad1, wfold);

    int blocks_m = (M_NODES * 64) / 256;      // 5000 blocks, 1 wave per node
    int lblocks  = (M_NODES * 2 + 255) / 256; // logits threads

    for (int tt = 0; tt < 2; ++tt) {
        logits1_kernel<<<lblocks, 256, 0, stream>>>(x, wfold, asv, adv, tt);
        agg1_kernel<<<blocks_m, 256, 0, stream>>>(offsets, ssrc, x, W1, asv, adv, b1, out1, tt);
        proj2_kernel<<<blocks_m, 256, 0, stream>>>(out1, W2, as2, ad2, h2p, asv, adv);
        agg2_kernel<<<blocks_m, 256, 0, stream>>>(offsets, ssrc, h2p, asv, adv, b2, h2, tt);
    }

    final_kernel<<<blocks_m, 256, 0, stream>>>(h2, wconv, bconv, wfc, bfc, out);
}

// Round 14
// 433.665 us; speedup vs baseline: 1.2757x; 1.1044x over previous
//
#include <hip/hip_runtime.h>
#include <math.h>

// Problem constants (fixed by setup_inputs):
// B=2, W=12, N=10000, F=16, HID=32, H=2, M=B*N=20000
// E0 total = 320000 edges; +M self loops => E_TOT = 340000
// Only t=10 and t=11 feed the final output (conv tail, last position).
#define M_NODES 20000
#define N_PER_B 10000
#define E0T     320000
#define E_TOT   340000

// ---------------- CSR build ----------------

__global__ void hist_kernel(const int* __restrict__ eidx, int* __restrict__ cnt) {
    int e = blockIdx.x * blockDim.x + threadIdx.x;
    if (e >= E_TOT) return;
    int d = (e < E0T) ? eidx[E0T + e] : (e - E0T);
    atomicAdd(&cnt[d], 1);
}

__global__ void scan_kernel(const int* __restrict__ cnt, int* __restrict__ offsets,
                            int* __restrict__ cursor) {
    __shared__ int sdata[1024];
    const int CHUNK = 20; // 1024*20 = 20480 >= 20000
    int tid = threadIdx.x;
    int begin = tid * CHUNK;
    int end = begin + CHUNK; if (end > M_NODES) end = M_NODES;
    if (begin > M_NODES) begin = M_NODES;
    int s = 0;
    for (int i = begin; i < end; ++i) s += cnt[i];
    sdata[tid] = s;
    __syncthreads();
    for (int off = 1; off < 1024; off <<= 1) {
        int v = (tid >= off) ? sdata[tid - off] : 0;
        __syncthreads();
        sdata[tid] += v;
        __syncthreads();
    }
    int run = (tid == 0) ? 0 : sdata[tid - 1];
    for (int i = begin; i < end; ++i) {
        offsets[i] = run; cursor[i] = run; run += cnt[i];
    }
    if (tid == 1023) offsets[M_NODES] = sdata[1023];
}

__global__ void scatter_kernel(const int* __restrict__ eidx, int* __restrict__ cursor,
                               int* __restrict__ ssrc) {
    int e = blockIdx.x * blockDim.x + threadIdx.x;
    if (e >= E_TOT) return;
    int s, d;
    if (e < E0T) { s = eidx[e]; d = eidx[E0T + e]; }
    else         { s = e - E0T; d = s; }
    int pos = atomicAdd(&cursor[d], 1);
    ssrc[pos] = s;
}

// Deterministic CSR: sort each dst bucket by src.
// One WAVE per bucket, bitonic sort across 64 lanes (avg deg 17, max ~40).
// Serial fallback on lane 0 if a bucket somehow exceeds 64.
__global__ void sort_kernel(const int* __restrict__ offsets, int* __restrict__ ssrc) {
    int w = (blockIdx.x * blockDim.x + threadIdx.x) >> 6;
    int lane = threadIdx.x & 63;
    if (w >= M_NODES) return;
    int s = offsets[w], e = offsets[w + 1];
    int len = e - s;
    if (len <= 1) return;
    if (len <= 64) {
        int v = (lane < len) ? ssrc[s + lane] : 0x7fffffff;
        #pragma unroll
        for (int k = 2; k <= 64; k <<= 1) {
            #pragma unroll
            for (int j = k >> 1; j > 0; j >>= 1) {
                int partner = __shfl_xor(v, j, 64);
                bool ascending = ((lane & k) == 0);
                bool lower = ((lane & j) == 0);
                bool keepMin = (lower == ascending);
                v = keepMin ? min(v, partner) : max(v, partner);
            }
        }
        if (lane < len) ssrc[s + lane] = v;
    } else if (lane == 0) {
        for (int i = s + 1; i < e; ++i) {
            int v = ssrc[i]; int j = i - 1;
            while (j >= s && ssrc[j] > v) { ssrc[j + 1] = ssrc[j]; --j; }
            ssrc[j + 1] = v;
        }
    }
}

// ---------------- layer-1 projection + logits ----------------
// wave per node; lane = output channel c in [0,64); head = lane>>5.
// Writes h1 row + per-head attention logits (shfl-reduce within each 32-lane head).
__global__ void proj1_kernel(const float* __restrict__ x, const float* __restrict__ W1,
                             const float* __restrict__ as1, const float* __restrict__ ad1,
                             float* __restrict__ h1, float* __restrict__ asv,
                             float* __restrict__ adv, int tt) {
    int w = (blockIdx.x * blockDim.x + threadIdx.x) >> 6;
    int lane = threadIdx.x & 63;
    if (w >= M_NODES) return;
    int b = w / N_PER_B, n = w - b * N_PER_B;
    const float* xr = x + ((size_t)((b * 12 + 10 + tt) * N_PER_B + n)) * 16;
    float acc = 0.f;
    #pragma unroll
    for (int f = 0; f < 16; ++f) acc += xr[f] * W1[f * 64 + lane];
    h1[(size_t)w * 64 + lane] = acc;
    float sv = acc * as1[lane];   // as1 flat (H,C) == lane
    float dv = acc * ad1[lane];
    #pragma unroll
    for (int off = 16; off >= 1; off >>= 1) {
        sv += __shfl_xor(sv, off, 64);
        dv += __shfl_xor(dv, off, 64);
    }
    if ((lane & 31) == 0) {
        asv[w * 2 + (lane >> 5)] = sv;
        adv[w * 2 + (lane >> 5)] = dv;
    }
}

// ---------------- layer-1 softmax-aggregate (gathers precomputed h1) ----------------
__global__ void agg1_kernel(const int* __restrict__ offsets, const int* __restrict__ ssrc,
                            const float* __restrict__ h1, const float* __restrict__ asv,
                            const float* __restrict__ adv, const float* __restrict__ b1,
                            float* __restrict__ out1) {
    int w = (blockIdx.x * blockDim.x + threadIdx.x) >> 6;
    int lane = threadIdx.x & 63;
    if (w >= M_NODES) return;
    int m = w;
    int head = lane >> 5, k = lane & 31;
    int start = offsets[m], end = offsets[m + 1];
    float ad = adv[m * 2 + head];
    float mx = -1e30f;
    for (int e = start + k; e < end; e += 32) {
        float v = asv[ssrc[e] * 2 + head] + ad;
        v = v > 0.f ? v : 0.2f * v;
        mx = fmaxf(mx, v);
    }
    #pragma unroll
    for (int off = 16; off >= 1; off >>= 1) mx = fmaxf(mx, __shfl_xor(mx, off, 64));
    float sm = 0.f;
    for (int e = start + k; e < end; e += 32) {
        float v = asv[ssrc[e] * 2 + head] + ad;
        v = v > 0.f ? v : 0.2f * v;
        sm += expf(v - mx);
    }
    #pragma unroll
    for (int off = 16; off >= 1; off >>= 1) sm += __shfl_xor(sm, off, 64);
    float inv = 1.f / sm;
    float acc = 0.f;
    for (int e = start; e < end; ++e) {
        int s = ssrc[e];
        float v = asv[s * 2 + head] + ad;
        v = v > 0.f ? v : 0.2f * v;
        acc += expf(v - mx) * inv * h1[(size_t)s * 64 + lane];
    }
    float r = acc + b1[lane];
    out1[(size_t)m * 64 + lane] = r > 0.f ? r : 0.f;
}

// ---------------- layer-2 projection + logits ----------------
__global__ void proj2_kernel(const float* __restrict__ out1, const float* __restrict__ W2,
                             const float* __restrict__ as2, const float* __restrict__ ad2,
                             float* __restrict__ h2p, float* __restrict__ asv, float* __restrict__ adv) {
    int w = (blockIdx.x * blockDim.x + threadIdx.x) >> 6;
    int lane = threadIdx.x & 63;
    if (w >= M_NODES) return;
    float xv = out1[(size_t)w * 64 + lane];
    float acc = 0.f;
    #pragma unroll
    for (int f = 0; f < 64; ++f) acc += __shfl(xv, f, 64) * W2[f * 64 + lane];
    h2p[(size_t)w * 64 + lane] = acc;
    float sv = acc * as2[lane];
    float dv = acc * ad2[lane];
    #pragma unroll
    for (int off = 16; off >= 1; off >>= 1) {
        sv += __shfl_xor(sv, off, 64);
        dv += __shfl_xor(dv, off, 64);
    }
    if ((lane & 31) == 0) {
        asv[w * 2 + (lane >> 5)] = sv;
        adv[w * 2 + (lane >> 5)] = dv;
    }
}

// ---------------- layer-2 softmax-aggregate (mean heads) ----------------
__global__ void agg2_kernel(const int* __restrict__ offsets, const int* __restrict__ ssrc,
                            const float* __restrict__ h2p, const float* __restrict__ asv,
                            const float* __restrict__ adv, const float* __restrict__ b2,
                            float* __restrict__ h2, int tt) {
    int w = (blockIdx.x * blockDim.x + threadIdx.x) >> 6;
    int lane = threadIdx.x & 63;
    if (w >= M_NODES) return;
    int m = w;
    int head = lane >> 5, k = lane & 31;
    int start = offsets[m], end = offsets[m + 1];
    float ad = adv[m * 2 + head];
    float mx = -1e30f;
    for (int e = start + k; e < end; e += 32) {
        float v = asv[ssrc[e] * 2 + head] + ad;
        v = v > 0.f ? v : 0.2f * v;
        mx = fmaxf(mx, v);
    }
    #pragma unroll
    for (int off = 16; off >= 1; off >>= 1) mx = fmaxf(mx, __shfl_xor(mx, off, 64));
    float sm = 0.f;
    for (int e = start + k; e < end; e += 32) {
        float v = asv[ssrc[e] * 2 + head] + ad;
        v = v > 0.f ? v : 0.2f * v;
        sm += expf(v - mx);
    }
    #pragma unroll
    for (int off = 16; off >= 1; off >>= 1) sm += __shfl_xor(sm, off, 64);
    float inv = 1.f / sm;
    float acc = 0.f;
    for (int e = start; e < end; ++e) {
        int s = ssrc[e];
        float v = asv[s * 2 + head] + ad;
        v = v > 0.f ? v : 0.2f * v;
        acc += expf(v - mx) * inv * h2p[(size_t)s * 64 + lane];
    }
    float other = __shfl_xor(acc, 32, 64);
    if (lane < 32) {
        float r = 0.5f * (acc + other) + b2[lane];
        h2[((size_t)tt * M_NODES + m) * 32 + lane] = r > 0.f ? r : 0.f;
    }
}

// ---------------- fused conv tail (last position) + FC ----------------
__global__ void final_kernel(const float* __restrict__ h2, const float* __restrict__ wconv,
                             const float* __restrict__ bconv, const float* __restrict__ wfc,
                             const float* __restrict__ bfc, float* __restrict__ out) {
    int w = (blockIdx.x * blockDim.x + threadIdx.x) >> 6;
    int lane = threadIdx.x & 63;
    if (w >= M_NODES) return;
    int m = w;
    int i = lane & 31, half = lane >> 5;  // half 0 -> t=10 (k=0), half 1 -> t=11 (k=1)
    float hv = h2[((size_t)half * M_NODES + m) * 32 + i];
    float acc = 0.f;
    for (int co = 0; co < 32; ++co) {
        float p = hv * wconv[(co * 32 + i) * 3 + half];
        #pragma unroll
        for (int off = 32; off >= 1; off >>= 1) p += __shfl_xor(p, off, 64);
        float t = p + bconv[co];
        t = t > 0.f ? t : 0.f;
        acc += t * wfc[co];
    }
    if (lane == 0) out[m] = acc + bfc[0];
}

extern "C" void kernel_launch(void* const* d_in, const int* in_sizes, int n_in,
                              void* d_out, int out_size, void* d_ws, size_t ws_size,
                              hipStream_t stream) {
    const float* x     = (const float*)d_in[0];
    const int*   eidx  = (const int*)d_in[1];
    const float* W1    = (const float*)d_in[2];
    const float* as1   = (const float*)d_in[3];
    const float* ad1   = (const float*)d_in[4];
    const float* b1    = (const float*)d_in[5];
    const float* W2    = (const float*)d_in[6];
    const float* as2   = (const float*)d_in[7];
    const float* ad2   = (const float*)d_in[8];
    const float* b2    = (const float*)d_in[9];
    const float* wconv = (const float*)d_in[10];
    const float* bconv = (const float*)d_in[11];
    const float* wfc   = (const float*)d_in[12];
    const float* bfc   = (const float*)d_in[13];
    float* out = (float*)d_out;

    // Workspace layout — total ~17.3 MB (kept well under ws_size).
    // hbuf is aliased: h1 during proj1->agg1, h2p during proj2->agg2 (disjoint live ranges).
    char* ws = (char*)d_ws;
    auto alloc = [&](size_t bytes) -> char* {
        char* p = ws;
        ws += (bytes + 255) & ~(size_t)255;
        return p;
    };
    int*   cnt     = (int*)alloc((M_NODES + 1) * sizeof(int));     // 80 KB
    int*   offsets = (int*)alloc((M_NODES + 1) * sizeof(int));     // 80 KB
    int*   cursor  = (int*)alloc((M_NODES + 1) * sizeof(int));     // 80 KB
    int*   ssrc    = (int*)alloc((size_t)E_TOT * sizeof(int));     // 1.36 MB
    float* asv     = (float*)alloc((size_t)M_NODES * 2 * sizeof(float)); // 160 KB
    float* adv     = (float*)alloc((size_t)M_NODES * 2 * sizeof(float)); // 160 KB
    float* out1    = (float*)alloc((size_t)M_NODES * 64 * sizeof(float)); // 5.12 MB (per-t)
    float* hbuf    = (float*)alloc((size_t)M_NODES * 64 * sizeof(float)); // 5.12 MB (h1 / h2p)
    float* h2      = (float*)alloc((size_t)2 * M_NODES * 32 * sizeof(float)); // 5.12 MB (both t)

    hipMemsetAsync(cnt, 0, (M_NODES + 1) * sizeof(int), stream);

    int ethreads = 256, eblocks = (E_TOT + ethreads - 1) / ethreads;
    hist_kernel<<<eblocks, ethreads, 0, stream>>>(eidx, cnt);
    scan_kernel<<<1, 1024, 0, stream>>>(cnt, offsets, cursor);
    scatter_kernel<<<eblocks, ethreads, 0, stream>>>(eidx, cursor, ssrc);
    // one wave per bucket: 20000 waves -> 5000 blocks of 256
    sort_kernel<<<(M_NODES * 64) / 256, 256, 0, stream>>>(offsets, ssrc);

    int blocks_m = (M_NODES * 64) / 256;      // 5000 blocks, 1 wave per node

    for (int tt = 0; tt < 2; ++tt) {
        proj1_kernel<<<blocks_m, 256, 0, stream>>>(x, W1, as1, ad1, hbuf, asv, adv, tt);
        agg1_kernel<<<blocks_m, 256, 0, stream>>>(offsets, ssrc, hbuf, asv, adv, b1, out1);
        proj2_kernel<<<blocks_m, 256, 0, stream>>>(out1, W2, as2, ad2, hbuf, asv, adv);
        agg2_kernel<<<blocks_m, 256, 0, stream>>>(offsets, ssrc, hbuf, asv, adv, b2, h2, tt);
    }

    final_kernel<<<blocks_m, 256, 0, stream>>>(h2, wconv, bconv, wfc, bfc, out);
}